// Round 1
// baseline (1889.072 us; speedup 1.0000x reference)
//
#include <hip/hip_runtime.h>
#include <math.h>

#define HID 512
#define NSTATE 4   // h, t1, t2, S(=s1+s2)
#define BK 16
#define TM 64      // points per block tile
#define TN 64      // output cols per block tile

// ---------------------------------------------------------------------------
// Layer-0 init: z = x@W0 + b0 ; a = tanh(z)
//   h  = a
//   t_i = (1-a^2) * W0[i,k]          (dz/dx_i = W0[i,:], d2z = 0)
//   S  = -2 a (1-a^2) * (W0[0,k]^2 + W0[1,k]^2)
// State layout: A[s][k][p]  (p contiguous, chunk-local, stride P)
// ---------------------------------------------------------------------------
__global__ __launch_bounds__(256) void pois_init(
    const float* __restrict__ x_int, const float* __restrict__ x_bnd,
    const float* __restrict__ W0, const float* __restrict__ b0,
    float* __restrict__ Aout, int P, int chunk_start, int NI, int NT)
{
    int pl = blockIdx.x * 256 + threadIdx.x;
    int k  = blockIdx.y;
    if (pl >= P) return;
    int gp = chunk_start + pl;
    if (gp >= NT) gp = 0;              // dummy pad points (excluded from loss)
    float xx, yy;
    if (gp < NI) { xx = x_int[2*gp];      yy = x_int[2*gp+1]; }
    else         { xx = x_bnd[2*(gp-NI)]; yy = x_bnd[2*(gp-NI)+1]; }
    float w0 = W0[k], w1 = W0[HID + k], bb = b0[k];
    float a = tanhf(xx*w0 + yy*w1 + bb);
    float g = 1.f - a*a;
    size_t sstride = (size_t)HID * P;
    size_t base = (size_t)k * P + pl;
    Aout[0*sstride + base] = a;
    Aout[1*sstride + base] = g * w0;
    Aout[2*sstride + base] = g * w1;
    Aout[3*sstride + base] = -2.f * a * g * (w0*w0 + w1*w1);
}

// ---------------------------------------------------------------------------
// Hidden-layer transition: for each state s: z_s = A_s @ W  (bias only on s=0)
// then tanh coupling:
//   a  = tanh(z_h + b)
//   h' = a ; t_i' = (1-a^2) z_ti ; S' = (1-a^2) z_S - 2a(1-a^2)(z_t1^2+z_t2^2)
// Tiled fp32 GEMM: block = 64 points x 64 cols x 4 states, thread = 4x4x4.
// ---------------------------------------------------------------------------
__global__ __launch_bounds__(256) void pois_trans(
    const float* __restrict__ Ain, const float* __restrict__ W,
    const float* __restrict__ b, float* __restrict__ Aout, int P)
{
    __shared__ __align__(16) float Als[BK][NSTATE * TM]; // [r][s*64+p]
    __shared__ __align__(16) float Wls[BK][TN];          // [r][c]

    int tid = threadIdx.x;
    int tx = tid & 15;          // col group: cols j0 + tx*4 .. +3
    int ty = tid >> 4;          // row group: points p0 + ty*4 .. +3
    int p0 = blockIdx.x * TM;
    int j0 = blockIdx.y * TN;
    size_t sstride = (size_t)HID * P;

    float acc[NSTATE][4][4];    // [s][pi][ji]
    #pragma unroll
    for (int s = 0; s < NSTATE; ++s)
        #pragma unroll
        for (int pi = 0; pi < 4; ++pi)
            #pragma unroll
            for (int ji = 0; ji < 4; ++ji) acc[s][pi][ji] = 0.f;

    // staging assignments
    int a_s = tid >> 6;         // 0..3 state
    int a_r = (tid >> 4) & 3;   // base r (plus 4*i)
    int a_p = (tid & 15) * 4;   // point quad
    int w_r = tid >> 4;         // 0..15
    int w_c = (tid & 15) * 4;   // col quad

    for (int kk = 0; kk < HID; kk += BK) {
        __syncthreads();
        // stage W tile: 16 x 64
        {
            float4 wv = *(const float4*)&W[(size_t)(kk + w_r) * HID + j0 + w_c];
            *(float4*)&Wls[w_r][w_c] = wv;
        }
        // stage A tile: 16 x 4 x 64
        #pragma unroll
        for (int i = 0; i < 4; ++i) {
            int r = a_r + 4*i;
            float4 av = *(const float4*)&Ain[(size_t)a_s * sstride + (size_t)(kk + r) * P + p0 + a_p];
            *(float4*)&Als[r][a_s * TM + a_p] = av;
        }
        __syncthreads();

        #pragma unroll
        for (int r = 0; r < BK; ++r) {
            float4 wv = *(const float4*)&Wls[r][tx * 4];
            float wr[4]; wr[0]=wv.x; wr[1]=wv.y; wr[2]=wv.z; wr[3]=wv.w;
            #pragma unroll
            for (int s = 0; s < NSTATE; ++s) {
                float4 av = *(const float4*)&Als[r][s * TM + ty * 4];
                float ar[4]; ar[0]=av.x; ar[1]=av.y; ar[2]=av.z; ar[3]=av.w;
                #pragma unroll
                for (int pi = 0; pi < 4; ++pi)
                    #pragma unroll
                    for (int ji = 0; ji < 4; ++ji)
                        acc[s][pi][ji] += ar[pi] * wr[ji];
            }
        }
    }

    // epilogue: tanh coupling + store (float4 over points)
    int pbase = p0 + ty * 4;
    #pragma unroll
    for (int ji = 0; ji < 4; ++ji) {
        int j = j0 + tx * 4 + ji;
        float bj = b[j];
        float4 vh, vt1, vt2, vS;
        float* ph  = (float*)&vh;
        float* pt1 = (float*)&vt1;
        float* pt2 = (float*)&vt2;
        float* pS  = (float*)&vS;
        #pragma unroll
        for (int pi = 0; pi < 4; ++pi) {
            float a  = tanhf(acc[0][pi][ji] + bj);
            float g  = 1.f - a * a;
            float t1 = acc[1][pi][ji];
            float t2 = acc[2][pi][ji];
            ph[pi]  = a;
            pt1[pi] = g * t1;
            pt2[pi] = g * t2;
            pS[pi]  = g * acc[3][pi][ji] - 2.f * a * g * (t1*t1 + t2*t2);
        }
        size_t base = (size_t)j * P + pbase;
        *(float4*)&Aout[0*sstride + base] = vh;
        *(float4*)&Aout[1*sstride + base] = vt1;
        *(float4*)&Aout[2*sstride + base] = vt2;
        *(float4*)&Aout[3*sstride + base] = vS;
    }
}

// ---------------------------------------------------------------------------
// Final layer + loss accumulation:
//   u   = h2 @ W3 + b3
//   lap = S  @ W3
//   interior: r = lap - f(x); acc[0] += r^2   |  boundary: acc[1] += u^2
// ---------------------------------------------------------------------------
__global__ __launch_bounds__(256) void pois_final(
    const float* __restrict__ A, const float* __restrict__ W3,
    const float* __restrict__ b3, const float* __restrict__ x_int,
    float* __restrict__ acc, int P, int chunk_start, int NI, int NT)
{
    __shared__ float w3s[HID];
    for (int k = threadIdx.x; k < HID; k += 256) w3s[k] = W3[k];
    __syncthreads();

    int pl = blockIdx.x * 256 + threadIdx.x;
    int gp = chunk_start + pl;
    float u = 0.f, lap = 0.f;
    if (pl < P) {
        const float* Ah = A;                       // s = 0
        const float* As = A + (size_t)3 * HID * P; // s = 3
        #pragma unroll 4
        for (int k = 0; k < HID; ++k) {
            float w = w3s[k];
            u   += Ah[(size_t)k * P + pl] * w;
            lap += As[(size_t)k * P + pl] * w;
        }
        u += b3[0];
    }
    float vi = 0.f, vb = 0.f;
    if (pl < P && gp < NI) {
        const float PIf = 3.14159265358979323846f;
        float xx = x_int[2*gp], yy = x_int[2*gp+1];
        float sx = sinf(PIf * xx);
        float y2 = yy * yy;
        float sy = sinf(PIf * y2), cy = cosf(PIf * y2);
        float f = -PIf*PIf * (1.f + 4.f*y2) * sx * sy + 2.f*PIf * sx * cy;
        float r = lap - f;
        vi = r * r;
    } else if (pl < P && gp < NT) {
        vb = u * u;
    }
    // reduce across block
    #pragma unroll
    for (int off = 32; off > 0; off >>= 1) {
        vi += __shfl_down(vi, off);
        vb += __shfl_down(vb, off);
    }
    __shared__ float redi[4], redb[4];
    int wave = threadIdx.x >> 6;
    if ((threadIdx.x & 63) == 0) { redi[wave] = vi; redb[wave] = vb; }
    __syncthreads();
    if (threadIdx.x == 0) {
        float si = redi[0] + redi[1] + redi[2] + redi[3];
        float sb = redb[0] + redb[1] + redb[2] + redb[3];
        atomicAdd(&acc[0], si);
        atomicAdd(&acc[1], sb);
    }
}

__global__ void pois_zero(float* acc) {
    if (threadIdx.x < 2) acc[threadIdx.x] = 0.f;
}

__global__ void pois_finish(const float* __restrict__ acc, float* __restrict__ out,
                            int NI, int NB)
{
    if (threadIdx.x == 0) {
        float inter = acc[0] / (float)NI;
        float bound = acc[1] / (float)NB;
        out[0] = 0.01f * inter + bound;  // ALPHA = 0.01
        out[1] = inter;
        out[2] = bound;
    }
}

// ---------------------------------------------------------------------------
extern "C" void kernel_launch(void* const* d_in, const int* in_sizes, int n_in,
                              void* d_out, int out_size, void* d_ws, size_t ws_size,
                              hipStream_t stream)
{
    const float* x_int = (const float*)d_in[0];
    const float* x_bnd = (const float*)d_in[1];
    const float* W0 = (const float*)d_in[2];
    const float* b0 = (const float*)d_in[3];
    const float* W1 = (const float*)d_in[4];
    const float* b1 = (const float*)d_in[5];
    const float* W2 = (const float*)d_in[6];
    const float* b2 = (const float*)d_in[7];
    const float* W3 = (const float*)d_in[8];
    const float* b3 = (const float*)d_in[9];

    int NI = in_sizes[0] / 2;   // 20000 interior
    int NB = in_sizes[1] / 2;   // 800 boundary
    int NT = NI + NB;           // 20800 (multiple of 64)

    // workspace: [acc: 1024B] [buf0: 4*HID*P floats] [buf1: 4*HID*P floats]
    float* acc = (float*)d_ws;
    long long pmax = ((long long)ws_size - 1024) / (2LL * NSTATE * HID * (long long)sizeof(float));
    pmax = (pmax / 64) * 64;
    int NTpad = ((NT + 63) / 64) * 64;
    int P = (pmax < (long long)NTpad) ? (int)pmax : NTpad;
    if (P < 64) P = 64;  // minimal fallback; assumes ws_size >= ~1 MB

    float* buf0 = (float*)((char*)d_ws + 1024);
    float* buf1 = buf0 + (size_t)NSTATE * HID * P;

    pois_zero<<<1, 64, 0, stream>>>(acc);

    int nchunks = (NT + P - 1) / P;
    for (int c = 0; c < nchunks; ++c) {
        int start = c * P;
        dim3 gi((P + 255) / 256, HID);
        pois_init<<<gi, 256, 0, stream>>>(x_int, x_bnd, W0, b0, buf0, P, start, NI, NT);
        dim3 gt(P / TM, HID / TN);
        pois_trans<<<gt, 256, 0, stream>>>(buf0, W1, b1, buf1, P);
        pois_trans<<<gt, 256, 0, stream>>>(buf1, W2, b2, buf0, P);
        pois_final<<<(P + 255) / 256, 256, 0, stream>>>(buf0, W3, b3, x_int, acc, P, start, NI, NT);
    }

    pois_finish<<<1, 64, 0, stream>>>(acc, (float*)d_out, NI, NB);
}

// Round 2
// 947.504 us; speedup vs baseline: 1.9937x; 1.9937x over previous
//
#include <hip/hip_runtime.h>
#include <math.h>

#define HID 512

typedef __attribute__((ext_vector_type(8))) short bf16x8;       // 8 bf16 = 4 VGPRs
typedef __attribute__((ext_vector_type(4))) float f32x4;
typedef __attribute__((ext_vector_type(4))) unsigned short us4;
typedef __attribute__((ext_vector_type(8))) unsigned short us8;

static __device__ __forceinline__ float fast_tanh(float x) {
    // tanh(x) = 1 - 2/(exp(2x)+1); safe at +/-inf of exp
    float e = __expf(2.f * x);
    return 1.f - 2.f / (e + 1.f);
}

static __device__ __forceinline__ unsigned short bf16_rne(float x) {
    unsigned int u = __float_as_uint(x);
    unsigned int r = u + 0x7fffu + ((u >> 16) & 1u);
    return (unsigned short)(r >> 16);
}
static __device__ __forceinline__ float bf16_f32(unsigned short h) {
    return __uint_as_float(((unsigned int)h) << 16);
}
static __device__ __forceinline__ void split2(float x, unsigned short& hi, unsigned short& lo) {
    hi = bf16_rne(x);
    lo = bf16_rne(x - bf16_f32(hi));
}

// ---------------------------------------------------------------------------
// W prep: out_hi/lo[j][k] = split(W[k][j])   (transpose + hi/lo split)
// ---------------------------------------------------------------------------
__global__ __launch_bounds__(256) void prep_w(
    const float* __restrict__ W, unsigned short* __restrict__ Whi,
    unsigned short* __restrict__ Wlo)
{
    int gid = blockIdx.x * 256 + threadIdx.x;   // over 512*512, k fastest
    int j = gid >> 9, k = gid & 511;
    float x = W[k * HID + j];
    unsigned short hi, lo; split2(x, hi, lo);
    Whi[gid] = hi; Wlo[gid] = lo;
}

// ---------------------------------------------------------------------------
// Layer-0 init -> split-bf16 state planes, layout A[s][hl][p][k] (k contiguous)
//   h = tanh(x@W0+b0); t_i = g*W0[i,k]; S = -2 a g (w0^2+w1^2)
// ---------------------------------------------------------------------------
__global__ __launch_bounds__(256) void pois_init(
    const float* __restrict__ x_int, const float* __restrict__ x_bnd,
    const float* __restrict__ W0, const float* __restrict__ b0,
    unsigned short* __restrict__ A, int Pc, int chunk_start, int NI, int NT)
{
    int gid = blockIdx.x * 256 + threadIdx.x;   // over Pc*512
    int p = gid >> 9, k = gid & 511;
    if (p >= Pc) return;
    int gp = chunk_start + p;
    if (gp >= NT) gp = 0;                        // dummy pad point
    float xx, yy;
    if (gp < NI) { xx = x_int[2*gp];      yy = x_int[2*gp+1]; }
    else         { xx = x_bnd[2*(gp-NI)]; yy = x_bnd[2*(gp-NI)+1]; }
    float w0 = W0[k], w1 = W0[HID + k], bb = b0[k];
    float a = fast_tanh(xx*w0 + yy*w1 + bb);
    float g = 1.f - a*a;
    float vals[4];
    vals[0] = a;
    vals[1] = g * w0;
    vals[2] = g * w1;
    vals[3] = -2.f * a * g * (w0*w0 + w1*w1);
    size_t shl = (size_t)Pc * HID;               // plane stride (elements)
    size_t base = (size_t)p * HID + k;
    #pragma unroll
    for (int s = 0; s < 4; ++s) {
        unsigned short hi, lo; split2(vals[s], hi, lo);
        A[(size_t)s * 2 * shl + base]       = hi;
        A[(size_t)s * 2 * shl + shl + base] = lo;
    }
}

// ---------------------------------------------------------------------------
// MFMA hidden-layer transition (split-bf16, 3-term product), no LDS.
// GEMM: D[j][p] = sum_k Wt[j][k] * A_s[p][k]   (MFMA A-op = W, B-op = state)
// Block: 64 j x 64 p x 4 states, 4 waves, wave w = p sub-tile [w*16, w*16+16)
// ---------------------------------------------------------------------------
__global__ __launch_bounds__(256, 2) void pois_trans(
    const unsigned short* __restrict__ Ain,   // [s][hl][p][k]
    const unsigned short* __restrict__ Whi,   // [j][k]
    const unsigned short* __restrict__ Wlo,   // [j][k]
    const float* __restrict__ b,
    unsigned short* __restrict__ Aout, int Pc)
{
    const int tid  = threadIdx.x;
    const int lane = tid & 63;
    const int wv   = tid >> 6;
    const int l15  = lane & 15;
    const int quad = lane >> 4;

    // XCD-co-locating swizzle: all 8 j-blocks of one p-tile share lid%8 -> one XCD
    int lid = blockIdx.x;
    int n = lid >> 3, x = lid & 7;
    int jb = n & 7;
    int pb = ((n >> 3) << 3) + x;
    int j0 = jb * 64;
    int p0 = pb * 64;

    const size_t shl = (size_t)Pc * HID;          // hi/lo plane stride
    const int prow = p0 + wv * 16 + l15;          // this thread's p (B-op n = l15)

    const size_t aoff = (size_t)prow * HID + quad * 8;
    const size_t woff = (size_t)(j0 + l15) * HID + quad * 8;

    f32x4 acc[4][4];                              // [state][j-tile]
    #pragma unroll
    for (int s = 0; s < 4; ++s)
        #pragma unroll
        for (int jt = 0; jt < 4; ++jt) acc[s][jt] = (f32x4)0.f;

    for (int k = 0; k < HID; k += 32) {
        bf16x8 wh[4], wl[4], ah[4], al[4];
        #pragma unroll
        for (int jt = 0; jt < 4; ++jt) {
            wh[jt] = *(const bf16x8*)(Whi + woff + (size_t)jt * 16 * HID + k);
            wl[jt] = *(const bf16x8*)(Wlo + woff + (size_t)jt * 16 * HID + k);
        }
        #pragma unroll
        for (int s = 0; s < 4; ++s) {
            ah[s] = *(const bf16x8*)(Ain + (size_t)s * 2 * shl + aoff + k);
            al[s] = *(const bf16x8*)(Ain + (size_t)s * 2 * shl + shl + aoff + k);
        }
        #pragma unroll
        for (int s = 0; s < 4; ++s)
            #pragma unroll
            for (int jt = 0; jt < 4; ++jt) {
                acc[s][jt] = __builtin_amdgcn_mfma_f32_16x16x32_bf16(wh[jt], ah[s], acc[s][jt], 0, 0, 0);
                acc[s][jt] = __builtin_amdgcn_mfma_f32_16x16x32_bf16(wh[jt], al[s], acc[s][jt], 0, 0, 0);
                acc[s][jt] = __builtin_amdgcn_mfma_f32_16x16x32_bf16(wl[jt], ah[s], acc[s][jt], 0, 0, 0);
            }
    }

    // Epilogue: tanh coupling; D row j = j0 + jt*16 + quad*4 + r, col p = prow.
    // Output layout [s][hl][p][j] (j contiguous) = next layer's [p][k].
    #pragma unroll
    for (int jt = 0; jt < 4; ++jt) {
        int jbase = j0 + jt * 16 + quad * 4;
        f32x4 bv = *(const f32x4*)&b[jbase];
        us4 oh[4], ol[4];                         // [state] packed over r
        #pragma unroll
        for (int r = 0; r < 4; ++r) {
            float a  = fast_tanh(acc[0][jt][r] + bv[r]);
            float g  = 1.f - a * a;
            float z1 = acc[1][jt][r];
            float z2 = acc[2][jt][r];
            float vals[4];
            vals[0] = a;
            vals[1] = g * z1;
            vals[2] = g * z2;
            vals[3] = g * acc[3][jt][r] - 2.f * a * g * (z1 * z1 + z2 * z2);
            #pragma unroll
            for (int s = 0; s < 4; ++s) {
                unsigned short hi, lo; split2(vals[s], hi, lo);
                oh[s][r] = hi; ol[s][r] = lo;
            }
        }
        size_t obase = (size_t)prow * HID + jbase;
        #pragma unroll
        for (int s = 0; s < 4; ++s) {
            *(us4*)(Aout + (size_t)s * 2 * shl + obase)       = oh[s];
            *(us4*)(Aout + (size_t)s * 2 * shl + shl + obase) = ol[s];
        }
    }
}

// ---------------------------------------------------------------------------
// Final layer + loss: one wave per point.
//   u = h.W3 + b3 ; lap = S.W3 ; interior: (lap-f)^2 ; boundary: u^2
// ---------------------------------------------------------------------------
__global__ __launch_bounds__(256) void pois_final(
    const unsigned short* __restrict__ A, const float* __restrict__ W3,
    const float* __restrict__ b3, const float* __restrict__ x_int,
    float* __restrict__ acc, int Pc, int chunk_start, int NI, int NT)
{
    int wv = threadIdx.x >> 6, lane = threadIdx.x & 63;
    int pl = blockIdx.x * 4 + wv;
    int gp = chunk_start + pl;
    size_t shl = (size_t)Pc * HID;

    float u = 0.f, lap = 0.f;
    {
        size_t base = (size_t)pl * HID + lane * 8;
        us8 hh = *(const us8*)(A + base);
        us8 hl = *(const us8*)(A + shl + base);
        us8 sh = *(const us8*)(A + 6 * shl + base);
        us8 sl = *(const us8*)(A + 7 * shl + base);
        f32x4 w3a = *(const f32x4*)&W3[lane * 8];
        f32x4 w3b = *(const f32x4*)&W3[lane * 8 + 4];
        #pragma unroll
        for (int t = 0; t < 8; ++t) {
            float w = (t < 4) ? w3a[t] : w3b[t - 4];
            u   += (bf16_f32(hh[t]) + bf16_f32(hl[t])) * w;
            lap += (bf16_f32(sh[t]) + bf16_f32(sl[t])) * w;
        }
    }
    #pragma unroll
    for (int off = 32; off > 0; off >>= 1) {
        u   += __shfl_down(u, off);
        lap += __shfl_down(lap, off);
    }

    __shared__ float redi[4], redb[4];
    if (lane == 0) {
        float vi = 0.f, vb = 0.f;
        if (gp < NI) {
            const float PIf = 3.14159265358979323846f;
            float xx = x_int[2 * gp], yy = x_int[2 * gp + 1];
            float sx = sinf(PIf * xx);
            float y2 = yy * yy;
            float sy = sinf(PIf * y2), cy = cosf(PIf * y2);
            float f = -PIf * PIf * (1.f + 4.f * y2) * sx * sy + 2.f * PIf * sx * cy;
            float r = lap - f;
            vi = r * r;
        } else if (gp < NT) {
            float uu = u + b3[0];
            vb = uu * uu;
        }
        redi[wv] = vi; redb[wv] = vb;
    }
    __syncthreads();
    if (threadIdx.x == 0) {
        atomicAdd(&acc[0], redi[0] + redi[1] + redi[2] + redi[3]);
        atomicAdd(&acc[1], redb[0] + redb[1] + redb[2] + redb[3]);
    }
}

__global__ void pois_zero(float* acc) {
    if (threadIdx.x < 2) acc[threadIdx.x] = 0.f;
}

__global__ void pois_finish(const float* __restrict__ acc, float* __restrict__ out,
                            int NI, int NB)
{
    if (threadIdx.x == 0) {
        float inter = acc[0] / (float)NI;
        float bound = acc[1] / (float)NB;
        out[0] = 0.01f * inter + bound;   // ALPHA = 0.01
        out[1] = inter;
        out[2] = bound;
    }
}

// ---------------------------------------------------------------------------
extern "C" void kernel_launch(void* const* d_in, const int* in_sizes, int n_in,
                              void* d_out, int out_size, void* d_ws, size_t ws_size,
                              hipStream_t stream)
{
    const float* x_int = (const float*)d_in[0];
    const float* x_bnd = (const float*)d_in[1];
    const float* W0 = (const float*)d_in[2];
    const float* b0 = (const float*)d_in[3];
    const float* W1 = (const float*)d_in[4];
    const float* b1 = (const float*)d_in[5];
    const float* W2 = (const float*)d_in[6];
    const float* b2 = (const float*)d_in[7];
    const float* W3 = (const float*)d_in[8];
    const float* b3 = (const float*)d_in[9];

    int NI = in_sizes[0] / 2;    // 20000
    int NB = in_sizes[1] / 2;    // 800
    int NT = NI + NB;            // 20800

    // ws layout: [acc 1KB][Wt1 hi|lo, Wt2 hi|lo: 4 x 512KB][A buf0][A buf1]
    float* acc = (float*)d_ws;
    unsigned short* wbuf = (unsigned short*)((char*)d_ws + 1024);
    unsigned short* w1hi = wbuf;
    unsigned short* w1lo = wbuf + 262144;
    unsigned short* w2hi = wbuf + 2 * 262144;
    unsigned short* w2lo = wbuf + 3 * 262144;
    unsigned short* abase = wbuf + 4 * 262144;

    long long avail = (long long)ws_size - 1024 - 4LL * 262144 * 2;
    // bytes per point for both buffers: 2 bufs * 4 states * 2 planes * 512 * 2B
    long long pmax = avail / 16384;
    pmax = (pmax / 512) * 512;
    int NTpad = ((NT + 511) / 512) * 512;        // 20992
    int Pfull = (pmax < (long long)NTpad) ? (int)pmax : NTpad;
    if (Pfull < 512) Pfull = 512;

    prep_w<<<1024, 256, 0, stream>>>(W1, w1hi, w1lo);
    prep_w<<<1024, 256, 0, stream>>>(W2, w2hi, w2lo);
    pois_zero<<<1, 64, 0, stream>>>(acc);

    for (int start = 0; start < NT; start += Pfull) {
        int rem = NT - start;
        int rempad = ((rem + 511) / 512) * 512;
        int Pc = (Pfull < rempad) ? Pfull : rempad;
        unsigned short* buf0 = abase;
        unsigned short* buf1 = abase + (size_t)4 * 2 * Pc * HID;

        pois_init<<<Pc * 2, 256, 0, stream>>>(x_int, x_bnd, W0, b0, buf0, Pc, start, NI, NT);
        int nblk = (Pc / 64) * 8;
        pois_trans<<<nblk, 256, 0, stream>>>(buf0, w1hi, w1lo, b1, buf1, Pc);
        pois_trans<<<nblk, 256, 0, stream>>>(buf1, w2hi, w2lo, b2, buf0, Pc);
        pois_final<<<Pc / 4, 256, 0, stream>>>(buf0, W3, b3, x_int, acc, Pc, start, NI, NT);
    }

    pois_finish<<<1, 64, 0, stream>>>(acc, (float*)d_out, NI, NB);
}

// Round 3
// 611.326 us; speedup vs baseline: 3.0901x; 1.5499x over previous
//
#include <hip/hip_runtime.h>
#include <math.h>

#define HID 512

typedef __attribute__((ext_vector_type(8))) short bf16x8;       // 8 bf16 = 4 VGPRs
typedef __attribute__((ext_vector_type(4))) float f32x4;
typedef __attribute__((ext_vector_type(4))) unsigned short us4;
typedef __attribute__((ext_vector_type(8))) unsigned short us8;

static __device__ __forceinline__ float fast_tanh(float x) {
    float e = __expf(2.f * x);
    return 1.f - 2.f / (e + 1.f);
}

static __device__ __forceinline__ unsigned short bf16_rne(float x) {
    unsigned int u = __float_as_uint(x);
    unsigned int r = u + 0x7fffu + ((u >> 16) & 1u);
    return (unsigned short)(r >> 16);
}
static __device__ __forceinline__ float bf16_f32(unsigned short h) {
    return __uint_as_float(((unsigned int)h) << 16);
}
static __device__ __forceinline__ void split2(float x, unsigned short& hi, unsigned short& lo) {
    hi = bf16_rne(x);
    lo = bf16_rne(x - bf16_f32(hi));
}

// async global->LDS, 16B per lane; lds must be wave-uniform base (HW adds lane*16)
static __device__ __forceinline__ void async_cp16(void* lds, const void* g) {
    __builtin_amdgcn_global_load_lds(
        (const __attribute__((address_space(1))) unsigned int*)g,
        (__attribute__((address_space(3))) unsigned int*)lds, 16, 0, 0);
}

// ---------------------------------------------------------------------------
// W prep: k-tiled transpose+split for LDS staging.
// Output layout: Wt[kb(16)][jb(8)][kgrp(4)][jl(64)][ko(8)]  (= W[j][k] split)
//   j = jb*64+jl, k = kb*32+kgrp*8+ko.  Each (kb,jb) slab = 2048 elems = 4KB,
//   contiguous, in exactly the order global_load_lds writes LDS.
// ---------------------------------------------------------------------------
__global__ __launch_bounds__(256) void prep_w(
    const float* __restrict__ W, unsigned short* __restrict__ Whi,
    unsigned short* __restrict__ Wlo)
{
    int gid = blockIdx.x * 256 + threadIdx.x;   // 0 .. 262143, output-linear
    int ko   = gid & 7;
    int jl   = (gid >> 3) & 63;
    int kgrp = (gid >> 9) & 3;
    int jb   = (gid >> 11) & 7;
    int kb   = gid >> 14;
    int j = jb * 64 + jl;
    int k = kb * 32 + kgrp * 8 + ko;
    float x = W[k * HID + j];
    unsigned short hi, lo; split2(x, hi, lo);
    Whi[gid] = hi; Wlo[gid] = lo;
}

// ---------------------------------------------------------------------------
// Layer-0 init -> split-bf16 state planes, layout A[s][hl][p][k] (k contiguous)
// ---------------------------------------------------------------------------
__global__ __launch_bounds__(256) void pois_init(
    const float* __restrict__ x_int, const float* __restrict__ x_bnd,
    const float* __restrict__ W0, const float* __restrict__ b0,
    unsigned short* __restrict__ A, int Pc, int chunk_start, int NI, int NT)
{
    int gid = blockIdx.x * 256 + threadIdx.x;   // over Pc*512
    int p = gid >> 9, k = gid & 511;
    if (p >= Pc) return;
    int gp = chunk_start + p;
    if (gp >= NT) gp = 0;                        // dummy pad point
    float xx, yy;
    if (gp < NI) { xx = x_int[2*gp];      yy = x_int[2*gp+1]; }
    else         { xx = x_bnd[2*(gp-NI)]; yy = x_bnd[2*(gp-NI)+1]; }
    float w0 = W0[k], w1 = W0[HID + k], bb = b0[k];
    float a = fast_tanh(xx*w0 + yy*w1 + bb);
    float g = 1.f - a*a;
    float vals[4];
    vals[0] = a;
    vals[1] = g * w0;
    vals[2] = g * w1;
    vals[3] = -2.f * a * g * (w0*w0 + w1*w1);
    size_t shl = (size_t)Pc * HID;               // plane stride (elements)
    size_t base = (size_t)p * HID + k;
    #pragma unroll
    for (int s = 0; s < 4; ++s) {
        unsigned short hi, lo; split2(vals[s], hi, lo);
        A[(size_t)s * 2 * shl + base]       = hi;
        A[(size_t)s * 2 * shl + shl + base] = lo;
    }
}

// ---------------------------------------------------------------------------
// MFMA hidden-layer transition (split-bf16, 3-term), W staged via
// global_load_lds double-buffer, A register-double-buffered.
// Block: 64 j x 64 p x 4 states, 4 waves; wave = 16 p.
// ---------------------------------------------------------------------------
__global__ __launch_bounds__(256, 2) void pois_trans(
    const unsigned short* __restrict__ Ain,   // [s][hl][p][k]
    const unsigned short* __restrict__ Whi,   // k-tiled (see prep_w)
    const unsigned short* __restrict__ Wlo,
    const float* __restrict__ b,
    unsigned short* __restrict__ Aout, int Pc)
{
    __shared__ unsigned short Wl[2][2][2048];  // [buf][hi/lo][kgrp*512+jl*8+ko]

    const int tid  = threadIdx.x;
    const int lane = tid & 63;
    const int wv   = tid >> 6;
    const int l15  = lane & 15;
    const int quad = lane >> 4;

    // XCD-co-locating swizzle: 8 j-blocks of a p-tile land on one XCD
    int lid = blockIdx.x;
    int n = lid >> 3, x = lid & 7;
    int jb = n & 7;
    int pb = ((n >> 3) << 3) + x;
    int j0 = jb * 64;
    int p0 = pb * 64;

    const size_t shl = (size_t)Pc * HID;          // hi/lo plane stride
    const int prow = p0 + wv * 16 + l15;          // B-op col n = l15
    const size_t aoff = (size_t)prow * HID + quad * 8;

    f32x4 acc[4][4];                              // [state][j-tile]
    #pragma unroll
    for (int s = 0; s < 4; ++s)
        #pragma unroll
        for (int jt = 0; jt < 4; ++jt) acc[s][jt] = (f32x4)0.f;

    // stage W slab for kb, buffer bf (4KB per plane; wave wv covers 1KB)
    auto stage = [&](int kb, int bf) {
        size_t slab = (size_t)(kb * 8 + jb) * 2048;
        int seg = wv * 512 + lane * 8;
        async_cp16(&Wl[bf][0][wv * 512], Whi + slab + seg);
        async_cp16(&Wl[bf][1][wv * 512], Wlo + slab + seg);
    };

    bf16x8 aCur[8], aNxt[8];                      // [0..3]=hi per state, [4..7]=lo
    auto loadA = [&](bf16x8* dst, int kpos) {
        #pragma unroll
        for (int s = 0; s < 4; ++s) {
            dst[s]     = *(const bf16x8*)(Ain + (size_t)(2*s)   * shl + aoff + kpos);
            dst[4 + s] = *(const bf16x8*)(Ain + (size_t)(2*s+1) * shl + aoff + kpos);
        }
    };

    stage(0, 0);
    loadA(aCur, 0);

    const int fbase = (quad * 64 + l15) * 8;      // frag elem offset (jt adds 128)

    #pragma unroll 2
    for (int kb = 0; kb < 16; ++kb) {
        __syncthreads();                          // stage(kb) + loads drained here
        int nb = kb + 1;
        if (nb < 16) {
            stage(nb, nb & 1);
            loadA(aNxt, nb * 32);
        }
        bf16x8 wh[4], wl[4];
        const unsigned short* Wh = &Wl[kb & 1][0][0];
        const unsigned short* Wlp = &Wl[kb & 1][1][0];
        #pragma unroll
        for (int jt = 0; jt < 4; ++jt) {
            wh[jt] = *(const bf16x8*)&Wh[fbase + jt * 128];
            wl[jt] = *(const bf16x8*)&Wlp[fbase + jt * 128];
        }
        #pragma unroll
        for (int s = 0; s < 4; ++s)
            #pragma unroll
            for (int jt = 0; jt < 4; ++jt) {
                acc[s][jt] = __builtin_amdgcn_mfma_f32_16x16x32_bf16(wh[jt], aCur[s],     acc[s][jt], 0, 0, 0);
                acc[s][jt] = __builtin_amdgcn_mfma_f32_16x16x32_bf16(wh[jt], aCur[4 + s], acc[s][jt], 0, 0, 0);
                acc[s][jt] = __builtin_amdgcn_mfma_f32_16x16x32_bf16(wl[jt], aCur[s],     acc[s][jt], 0, 0, 0);
            }
        #pragma unroll
        for (int i = 0; i < 8; ++i) aCur[i] = aNxt[i];
    }

    // Epilogue: tanh coupling; D row j = j0 + jt*16 + quad*4 + r, col p = prow.
    // Output layout [s][hl][p][j] = next layer's [p][k].
    #pragma unroll
    for (int jt = 0; jt < 4; ++jt) {
        int jbase = j0 + jt * 16 + quad * 4;
        f32x4 bv = *(const f32x4*)&b[jbase];
        us4 oh[4], ol[4];
        #pragma unroll
        for (int r = 0; r < 4; ++r) {
            float a  = fast_tanh(acc[0][jt][r] + bv[r]);
            float g  = 1.f - a * a;
            float z1 = acc[1][jt][r];
            float z2 = acc[2][jt][r];
            float vals[4];
            vals[0] = a;
            vals[1] = g * z1;
            vals[2] = g * z2;
            vals[3] = g * acc[3][jt][r] - 2.f * a * g * (z1 * z1 + z2 * z2);
            #pragma unroll
            for (int s = 0; s < 4; ++s) {
                unsigned short hi, lo; split2(vals[s], hi, lo);
                oh[s][r] = hi; ol[s][r] = lo;
            }
        }
        size_t obase = (size_t)prow * HID + jbase;
        #pragma unroll
        for (int s = 0; s < 4; ++s) {
            *(us4*)(Aout + (size_t)s * 2 * shl + obase)       = oh[s];
            *(us4*)(Aout + (size_t)s * 2 * shl + shl + obase) = ol[s];
        }
    }
}

// ---------------------------------------------------------------------------
// Final layer + loss: grid-stride, one wave per point per step,
// per-block partials -> 2 atomics per block (contention fix).
// ---------------------------------------------------------------------------
__global__ __launch_bounds__(256) void pois_final(
    const unsigned short* __restrict__ A, const float* __restrict__ W3,
    const float* __restrict__ b3, const float* __restrict__ x_int,
    float* __restrict__ acc, int Pc, int chunk_start, int NI, int NT,
    int nwaves)
{
    int wv = threadIdx.x >> 6, lane = threadIdx.x & 63;
    int gwave = blockIdx.x * 4 + wv;
    size_t shl = (size_t)Pc * HID;

    f32x4 w3a = *(const f32x4*)&W3[lane * 8];
    f32x4 w3b = *(const f32x4*)&W3[lane * 8 + 4];

    float vi_acc = 0.f, vb_acc = 0.f;
    for (int pl = gwave; pl < Pc; pl += nwaves) {
        int gp = chunk_start + pl;
        if (gp >= NT) break;                      // wave-uniform, monotone
        size_t base = (size_t)pl * HID + lane * 8;
        us8 hh = *(const us8*)(A + base);
        us8 hl = *(const us8*)(A + shl + base);
        us8 sh = *(const us8*)(A + 6 * shl + base);
        us8 sl = *(const us8*)(A + 7 * shl + base);
        float u = 0.f, lap = 0.f;
        #pragma unroll
        for (int t = 0; t < 8; ++t) {
            float w = (t < 4) ? w3a[t] : w3b[t - 4];
            u   += (bf16_f32(hh[t]) + bf16_f32(hl[t])) * w;
            lap += (bf16_f32(sh[t]) + bf16_f32(sl[t])) * w;
        }
        #pragma unroll
        for (int off = 32; off > 0; off >>= 1) {
            u   += __shfl_xor(u, off);
            lap += __shfl_xor(lap, off);
        }
        if (gp < NI) {
            const float PIf = 3.14159265358979323846f;
            float xx = x_int[2 * gp], yy = x_int[2 * gp + 1];
            float sx = sinf(PIf * xx);
            float y2 = yy * yy;
            float sy = sinf(PIf * y2), cy = cosf(PIf * y2);
            float f = -PIf * PIf * (1.f + 4.f * y2) * sx * sy + 2.f * PIf * sx * cy;
            float r = lap - f;
            vi_acc += r * r;
        } else {
            float uu = u + b3[0];
            vb_acc += uu * uu;
        }
    }

    __shared__ float redi[4], redb[4];
    if (lane == 0) { redi[wv] = vi_acc; redb[wv] = vb_acc; }
    __syncthreads();
    if (threadIdx.x == 0) {
        atomicAdd(&acc[0], redi[0] + redi[1] + redi[2] + redi[3]);
        atomicAdd(&acc[1], redb[0] + redb[1] + redb[2] + redb[3]);
    }
}

__global__ void pois_zero(float* acc) {
    if (threadIdx.x < 2) acc[threadIdx.x] = 0.f;
}

__global__ void pois_finish(const float* __restrict__ acc, float* __restrict__ out,
                            int NI, int NB)
{
    if (threadIdx.x == 0) {
        float inter = acc[0] / (float)NI;
        float bound = acc[1] / (float)NB;
        out[0] = 0.01f * inter + bound;   // ALPHA = 0.01
        out[1] = inter;
        out[2] = bound;
    }
}

// ---------------------------------------------------------------------------
extern "C" void kernel_launch(void* const* d_in, const int* in_sizes, int n_in,
                              void* d_out, int out_size, void* d_ws, size_t ws_size,
                              hipStream_t stream)
{
    const float* x_int = (const float*)d_in[0];
    const float* x_bnd = (const float*)d_in[1];
    const float* W0 = (const float*)d_in[2];
    const float* b0 = (const float*)d_in[3];
    const float* W1 = (const float*)d_in[4];
    const float* b1 = (const float*)d_in[5];
    const float* W2 = (const float*)d_in[6];
    const float* b2 = (const float*)d_in[7];
    const float* W3 = (const float*)d_in[8];
    const float* b3 = (const float*)d_in[9];

    int NI = in_sizes[0] / 2;    // 20000
    int NB = in_sizes[1] / 2;    // 800
    int NT = NI + NB;            // 20800

    float* acc = (float*)d_ws;
    unsigned short* wbuf = (unsigned short*)((char*)d_ws + 1024);
    unsigned short* w1hi = wbuf;
    unsigned short* w1lo = wbuf + 262144;
    unsigned short* w2hi = wbuf + 2 * 262144;
    unsigned short* w2lo = wbuf + 3 * 262144;
    unsigned short* abase = wbuf + 4 * 262144;

    long long avail = (long long)ws_size - 1024 - 4LL * 262144 * 2;
    long long pmax = avail / 16384;               // 2 bufs * 8 planes * 512 * 2B
    pmax = (pmax / 512) * 512;
    int NTpad = ((NT + 511) / 512) * 512;         // 20992
    int Pfull = (pmax < (long long)NTpad) ? (int)pmax : NTpad;
    if (Pfull < 512) Pfull = 512;

    prep_w<<<1024, 256, 0, stream>>>(W1, w1hi, w1lo);
    prep_w<<<1024, 256, 0, stream>>>(W2, w2hi, w2lo);
    pois_zero<<<1, 64, 0, stream>>>(acc);

    for (int start = 0; start < NT; start += Pfull) {
        int rem = NT - start;
        int rempad = ((rem + 511) / 512) * 512;
        int Pc = (Pfull < rempad) ? Pfull : rempad;
        unsigned short* buf0 = abase;
        unsigned short* buf1 = abase + (size_t)4 * 2 * Pc * HID;

        pois_init<<<Pc * 2, 256, 0, stream>>>(x_int, x_bnd, W0, b0, buf0, Pc, start, NI, NT);
        int nblk = (Pc / 64) * 8;
        pois_trans<<<nblk, 256, 0, stream>>>(buf0, w1hi, w1lo, b1, buf1, Pc);
        pois_trans<<<nblk, 256, 0, stream>>>(buf1, w2hi, w2lo, b2, buf0, Pc);
        pois_final<<<256, 256, 0, stream>>>(buf0, W3, b3, x_int, acc, Pc, start, NI, NT, 1024);
    }

    pois_finish<<<1, 64, 0, stream>>>(acc, (float*)d_out, NI, NB);
}

// Round 4
// 442.363 us; speedup vs baseline: 4.2704x; 1.3820x over previous
//
#include <hip/hip_runtime.h>
#include <math.h>

#define HID 512
#define KP 520              // padded k-row (+8 fp16 = 16B) to break bank conflicts

typedef __attribute__((ext_vector_type(8))) _Float16 half8;   // 4 VGPRs, MFMA frag
typedef __attribute__((ext_vector_type(4))) _Float16 half4;
typedef __attribute__((ext_vector_type(4))) float f32x4;

static __device__ __forceinline__ float fast_tanh(float x) {
    float e = __expf(2.f * x);
    return 1.f - 2.f / (e + 1.f);
}

// ---------------------------------------------------------------------------
// W prep: Wh/Wl[j][k] = fp16-split of W[k][j]  (transpose + hi/lo split)
// ---------------------------------------------------------------------------
__global__ __launch_bounds__(256) void prep_wt(
    const float* __restrict__ W, _Float16* __restrict__ Wh, _Float16* __restrict__ Wl)
{
    int gid = blockIdx.x * 256 + threadIdx.x;    // output-linear over [j][k]
    int j = gid >> 9, k = gid & 511;
    float x = W[k * HID + j];
    _Float16 hi = (_Float16)x;
    _Float16 lo = (_Float16)(x - (float)hi);
    Wh[gid] = hi; Wl[gid] = lo;
}

// ---------------------------------------------------------------------------
// One hidden-layer pass inside the fused kernel.
// A (B-op) in LDS Als[s][p][k]; W (A-op) streamed from global (L2-resident).
// Wave wv owns j in [128*wv, 128*wv+128).  2-term split product:
//   z = Wh*A + Wl*A   (A pure fp16; dropped error ~2^-11 relative)
// FULL: emit h,t1,t2,S planes; else only h,S (last hidden layer).
// ---------------------------------------------------------------------------
template<bool FULL>
static __device__ __forceinline__ void layer_pass(
    const _Float16* __restrict__ Wh, const _Float16* __restrict__ Wl,
    const float* __restrict__ bias,
    _Float16 (*Als)[16][KP], int wv, int lane)
{
    const int l15 = lane & 15, quad = lane >> 4;
    const int j0w = wv * 128;

    f32x4 acc[4][8];
    #pragma unroll
    for (int s = 0; s < 4; ++s)
        #pragma unroll
        for (int jt = 0; jt < 8; ++jt) acc[s][jt] = (f32x4)0.f;

    const size_t wbase = (size_t)(j0w + l15) * HID + quad * 8;

    #pragma unroll 2
    for (int kb = 0; kb < 16; ++kb) {
        const int k = kb * 32 + quad * 8;
        half8 a[4];
        #pragma unroll
        for (int s = 0; s < 4; ++s) a[s] = *(const half8*)&Als[s][l15][k];
        half8 wh[8], wl[8];
        #pragma unroll
        for (int jt = 0; jt < 8; ++jt) {
            wh[jt] = *(const half8*)(Wh + wbase + (size_t)jt * 16 * HID + kb * 32);
            wl[jt] = *(const half8*)(Wl + wbase + (size_t)jt * 16 * HID + kb * 32);
        }
        #pragma unroll
        for (int s = 0; s < 4; ++s)
            #pragma unroll
            for (int jt = 0; jt < 8; ++jt) {
                acc[s][jt] = __builtin_amdgcn_mfma_f32_16x16x32_f16(wh[jt], a[s], acc[s][jt], 0, 0, 0);
                acc[s][jt] = __builtin_amdgcn_mfma_f32_16x16x32_f16(wl[jt], a[s], acc[s][jt], 0, 0, 0);
            }
    }

    __syncthreads();   // all waves done reading Als; safe to overwrite

    // epilogue: tanh coupling; D row m = j-offset = jt*16+quad*4+r, col n = p = l15
    #pragma unroll
    for (int jt = 0; jt < 8; ++jt) {
        const int jb = j0w + jt * 16 + quad * 4;   // 4 consecutive j
        f32x4 bv = *(const f32x4*)&bias[jb];
        half4 vh, vt1, vt2, vS;
        #pragma unroll
        for (int r = 0; r < 4; ++r) {
            float a  = fast_tanh(acc[0][jt][r] + bv[r]);
            float g  = 1.f - a * a;
            float z1 = acc[1][jt][r];
            float z2 = acc[2][jt][r];
            vh[r] = (_Float16)a;
            if (FULL) {
                vt1[r] = (_Float16)(g * z1);
                vt2[r] = (_Float16)(g * z2);
            }
            vS[r] = (_Float16)(g * acc[3][jt][r] - 2.f * a * g * (z1 * z1 + z2 * z2));
        }
        *(half4*)&Als[0][l15][jb] = vh;
        if (FULL) {
            *(half4*)&Als[1][l15][jb] = vt1;
            *(half4*)&Als[2][l15][jb] = vt2;
        }
        *(half4*)&Als[3][l15][jb] = vS;
    }
    __syncthreads();   // Als(next layer) complete
}

// ---------------------------------------------------------------------------
// Fused: layer0 init -> L1 -> L2 -> final dot + loss partials. 16 pts/block.
// ---------------------------------------------------------------------------
__global__ __launch_bounds__(256, 2) void pois_fused(
    const float* __restrict__ x_int, const float* __restrict__ x_bnd,
    const float* __restrict__ W0, const float* __restrict__ b0,
    const _Float16* __restrict__ W1h, const _Float16* __restrict__ W1l,
    const float* __restrict__ b1,
    const _Float16* __restrict__ W2h, const _Float16* __restrict__ W2l,
    const float* __restrict__ b2,
    const float* __restrict__ W3, const float* __restrict__ b3,
    float* __restrict__ partials, int NI, int NT, int nblk)
{
    __shared__ _Float16 Als[4][16][KP];      // [state][p][k], 65 KB
    __shared__ float sc[32];

    const int tid = threadIdx.x;
    const int wv = tid >> 6, lane = tid & 63;
    const int p0 = blockIdx.x * 16;

    // ---- layer 0: thread (p = tid&15, kc = tid>>4) covers 32 k ----
    {
        const int p = tid & 15, kc = tid >> 4;
        int gp = p0 + p;
        int gpc = (gp >= NT) ? 0 : gp;
        float xx, yy;
        if (gpc < NI) { xx = x_int[2 * gpc];        yy = x_int[2 * gpc + 1]; }
        else          { xx = x_bnd[2 * (gpc - NI)]; yy = x_bnd[2 * (gpc - NI) + 1]; }
        #pragma unroll
        for (int k8 = 0; k8 < 4; ++k8) {
            const int k = kc * 32 + k8 * 8;
            f32x4 w0a = *(const f32x4*)&W0[k],       w0b = *(const f32x4*)&W0[k + 4];
            f32x4 w1a = *(const f32x4*)&W0[HID + k], w1b = *(const f32x4*)&W0[HID + k + 4];
            f32x4 b0a = *(const f32x4*)&b0[k],       b0b = *(const f32x4*)&b0[k + 4];
            half8 vh, vt1, vt2, vS;
            #pragma unroll
            for (int i = 0; i < 8; ++i) {
                float w0i = (i < 4) ? w0a[i] : w0b[i - 4];
                float w1i = (i < 4) ? w1a[i] : w1b[i - 4];
                float bbi = (i < 4) ? b0a[i] : b0b[i - 4];
                float a = fast_tanh(xx * w0i + yy * w1i + bbi);
                float g = 1.f - a * a;
                vh[i]  = (_Float16)a;
                vt1[i] = (_Float16)(g * w0i);
                vt2[i] = (_Float16)(g * w1i);
                vS[i]  = (_Float16)(-2.f * a * g * (w0i * w0i + w1i * w1i));
            }
            *(half8*)&Als[0][p][k] = vh;
            *(half8*)&Als[1][p][k] = vt1;
            *(half8*)&Als[2][p][k] = vt2;
            *(half8*)&Als[3][p][k] = vS;
        }
    }
    __syncthreads();

    layer_pass<true >(W1h, W1l, b1, Als, wv, lane);
    layer_pass<false>(W2h, W2l, b2, Als, wv, lane);

    // ---- final: u = h.W3 + b3 ; lap = S.W3 ; loss partials ----
    {
        const int psub = lane >> 4, kc = lane & 15;
        const int p = wv * 4 + psub;
        float u = 0.f, lap = 0.f;
        #pragma unroll
        for (int k8 = 0; k8 < 4; ++k8) {
            const int k = kc * 32 + k8 * 8;
            half8 hh = *(const half8*)&Als[0][p][k];
            half8 ss = *(const half8*)&Als[3][p][k];
            f32x4 wa = *(const f32x4*)&W3[k], wb = *(const f32x4*)&W3[k + 4];
            #pragma unroll
            for (int i = 0; i < 8; ++i) {
                float w = (i < 4) ? wa[i] : wb[i - 4];
                u   += (float)hh[i] * w;
                lap += (float)ss[i] * w;
            }
        }
        #pragma unroll
        for (int off = 1; off < 16; off <<= 1) {
            u   += __shfl_xor(u, off);
            lap += __shfl_xor(lap, off);
        }
        if (kc == 0) {
            int gp = p0 + p;
            float vi = 0.f, vb = 0.f;
            if (gp < NI) {
                const float PIf = 3.14159265358979323846f;
                float xx = x_int[2 * gp], yy = x_int[2 * gp + 1];
                float sx = sinf(PIf * xx);
                float y2 = yy * yy;
                float sy = sinf(PIf * y2), cy = cosf(PIf * y2);
                float f = -PIf * PIf * (1.f + 4.f * y2) * sx * sy + 2.f * PIf * sx * cy;
                float r = lap - f;
                vi = r * r;
            } else if (gp < NT) {
                float uu = u + b3[0];
                vb = uu * uu;
            }
            sc[p * 2] = vi; sc[p * 2 + 1] = vb;
        }
    }
    __syncthreads();
    if (tid == 0) {
        float svi = 0.f, svb = 0.f;
        #pragma unroll
        for (int p = 0; p < 16; ++p) { svi += sc[p * 2]; svb += sc[p * 2 + 1]; }
        partials[blockIdx.x] = svi;
        partials[nblk + blockIdx.x] = svb;
    }
}

// ---------------------------------------------------------------------------
// Deterministic final reduction (no atomics)
// ---------------------------------------------------------------------------
__global__ __launch_bounds__(256) void pois_reduce(
    const float* __restrict__ partials, float* __restrict__ out,
    int nblk, int NI, int NB)
{
    int tid = threadIdx.x;
    float si = 0.f, sb = 0.f;
    for (int i = tid; i < nblk; i += 256) {
        si += partials[i];
        sb += partials[nblk + i];
    }
    #pragma unroll
    for (int off = 32; off > 0; off >>= 1) {
        si += __shfl_xor(si, off);
        sb += __shfl_xor(sb, off);
    }
    __shared__ float ri[4], rb[4];
    int wv = tid >> 6;
    if ((tid & 63) == 0) { ri[wv] = si; rb[wv] = sb; }
    __syncthreads();
    if (tid == 0) {
        float inter = (ri[0] + ri[1] + ri[2] + ri[3]) / (float)NI;
        float bound = (rb[0] + rb[1] + rb[2] + rb[3]) / (float)NB;
        out[0] = 0.01f * inter + bound;   // ALPHA = 0.01
        out[1] = inter;
        out[2] = bound;
    }
}

// ---------------------------------------------------------------------------
extern "C" void kernel_launch(void* const* d_in, const int* in_sizes, int n_in,
                              void* d_out, int out_size, void* d_ws, size_t ws_size,
                              hipStream_t stream)
{
    const float* x_int = (const float*)d_in[0];
    const float* x_bnd = (const float*)d_in[1];
    const float* W0 = (const float*)d_in[2];
    const float* b0 = (const float*)d_in[3];
    const float* W1 = (const float*)d_in[4];
    const float* b1 = (const float*)d_in[5];
    const float* W2 = (const float*)d_in[6];
    const float* b2 = (const float*)d_in[7];
    const float* W3 = (const float*)d_in[8];
    const float* b3 = (const float*)d_in[9];

    int NI = in_sizes[0] / 2;    // 20000
    int NB = in_sizes[1] / 2;    // 800
    int NT = NI + NB;            // 20800
    int nblk = (NT + 15) / 16;   // 1300

    // ws: [partials 2*nblk floats, 16KB region][W1h|W1l|W2h|W2l 512KB each]
    float* partials = (float*)d_ws;
    _Float16* wsp = (_Float16*)((char*)d_ws + 16384);
    _Float16* W1h = wsp;
    _Float16* W1l = wsp + 262144;
    _Float16* W2h = wsp + 2 * 262144;
    _Float16* W2l = wsp + 3 * 262144;

    prep_wt<<<1024, 256, 0, stream>>>(W1, W1h, W1l);
    prep_wt<<<1024, 256, 0, stream>>>(W2, W2h, W2l);

    pois_fused<<<nblk, 256, 0, stream>>>(
        x_int, x_bnd, W0, b0, W1h, W1l, b1, W2h, W2l, b2, W3, b3,
        partials, NI, NT, nblk);

    pois_reduce<<<1, 256, 0, stream>>>(partials, (float*)d_out, nblk, NI, NB);
}

// Round 5
// 180.786 us; speedup vs baseline: 10.4492x; 2.4469x over previous
//
#include <hip/hip_runtime.h>
#include <math.h>

#define HID 512
#define KP 520              // padded k-row (+8 fp16 = 16B): conflict-free b128 groups
#define PPB 32              // points per block

typedef __attribute__((ext_vector_type(8))) _Float16 half8;   // 4 VGPRs, MFMA frag
typedef __attribute__((ext_vector_type(4))) _Float16 half4;
typedef __attribute__((ext_vector_type(4))) float f32x4;

static __device__ __forceinline__ float fast_tanh(float x) {
    float e = __expf(2.f * x);
    return 1.f - 2.f / (e + 1.f);
}

// ---------------------------------------------------------------------------
// W prep: single fp16 plane, slab layout for fully-coalesced frag loads:
//   Wh[jb(32)][kb(16)][l15(16)][quad(4)][k8(8)]  ; j = jb*16+l15, k = kb*32+quad*8+k8
// Each (jb,kb) slab = 512 elems = 1 KB contiguous; a wave frag-load reads one
// whole slab as 64 lanes x 16 B.
// ---------------------------------------------------------------------------
__global__ __launch_bounds__(256) void prep_wt(
    const float* __restrict__ W, _Float16* __restrict__ Wh)
{
    int gid = blockIdx.x * 256 + threadIdx.x;    // output-linear
    int k8   = gid & 7;
    int quad = (gid >> 3) & 3;
    int l15  = (gid >> 5) & 15;
    int kb   = (gid >> 9) & 15;
    int jb   = gid >> 13;
    int j = jb * 16 + l15;
    int k = kb * 32 + quad * 8 + k8;
    Wh[gid] = (_Float16)W[k * HID + j];
}

// ---------------------------------------------------------------------------
// One hidden-layer pass. A (B-op) in LDS Als[s][p][k]; W (A-op) streamed from
// L2 in 1KB slabs with ping-pong register prefetch. Wave wv owns j in
// [64*wv, 64*wv+64); 2 p-frags (p = l15, l15+16); 4 states.
// z = Wh*A (single-term; W fp16 rounding ~2^-11 relative, random-signed).
// FULL: emit h,t1,t2,S planes; else only h,S.
// ---------------------------------------------------------------------------
template<bool FULL>
static __device__ __forceinline__ void layer_pass(
    const _Float16* __restrict__ Wh, const float* __restrict__ bias,
    _Float16 (*Als)[PPB][KP], int wv, int lane)
{
    const int l15 = lane & 15, quad = lane >> 4;
    const int j0w = wv * 64;
    const int jb0 = wv * 4;                 // first 16-j slab group
    const int foff = l15 * 32 + quad * 8;   // lane offset within 1KB slab

    f32x4 acc[4][2][4];                     // [state][pf][jt]
    #pragma unroll
    for (int s = 0; s < 4; ++s)
        #pragma unroll
        for (int pf = 0; pf < 2; ++pf)
            #pragma unroll
            for (int jt = 0; jt < 4; ++jt) acc[s][pf][jt] = (f32x4)0.f;

    half8 wA[4], wB[4];
    #pragma unroll
    for (int jt = 0; jt < 4; ++jt)
        wA[jt] = *(const half8*)(Wh + (size_t)((jb0 + jt) * 16) * 512 + foff);

    auto iter = [&](int kb, half8 (&wc)[4], half8 (&wn)[4]) {
        half8 a[2][4];
        #pragma unroll
        for (int pf = 0; pf < 2; ++pf)
            #pragma unroll
            for (int s = 0; s < 4; ++s)
                a[pf][s] = *(const half8*)&Als[s][pf * 16 + l15][kb * 32 + quad * 8];
        if (kb < 15) {
            #pragma unroll
            for (int jt = 0; jt < 4; ++jt)
                wn[jt] = *(const half8*)(Wh + (size_t)((jb0 + jt) * 16 + kb + 1) * 512 + foff);
        }
        #pragma unroll
        for (int s = 0; s < 4; ++s)
            #pragma unroll
            for (int pf = 0; pf < 2; ++pf)
                #pragma unroll
                for (int jt = 0; jt < 4; ++jt)
                    acc[s][pf][jt] = __builtin_amdgcn_mfma_f32_16x16x32_f16(
                        wc[jt], a[pf][s], acc[s][pf][jt], 0, 0, 0);
    };

    #pragma unroll
    for (int kb = 0; kb < 16; kb += 2) {
        iter(kb,     wA, wB);
        iter(kb + 1, wB, wA);
    }

    __syncthreads();   // all waves done reading Als; safe to overwrite

    // epilogue: D row m = jt*16+quad*4+r (j-offset), col n = p = pf*16+l15
    #pragma unroll
    for (int jt = 0; jt < 4; ++jt) {
        const int jbase = j0w + jt * 16 + quad * 4;
        f32x4 bv = *(const f32x4*)&bias[jbase];
        #pragma unroll
        for (int pf = 0; pf < 2; ++pf) {
            const int p = pf * 16 + l15;
            half4 vh, vt1, vt2, vS;
            #pragma unroll
            for (int r = 0; r < 4; ++r) {
                float a  = fast_tanh(acc[0][pf][jt][r] + bv[r]);
                float g  = 1.f - a * a;
                float z1 = acc[1][pf][jt][r];
                float z2 = acc[2][pf][jt][r];
                vh[r] = (_Float16)a;
                if (FULL) {
                    vt1[r] = (_Float16)(g * z1);
                    vt2[r] = (_Float16)(g * z2);
                }
                vS[r] = (_Float16)(g * acc[3][pf][jt][r] - 2.f * a * g * (z1 * z1 + z2 * z2));
            }
            *(half4*)&Als[0][p][jbase] = vh;
            if (FULL) {
                *(half4*)&Als[1][p][jbase] = vt1;
                *(half4*)&Als[2][p][jbase] = vt2;
            }
            *(half4*)&Als[3][p][jbase] = vS;
        }
    }
    __syncthreads();   // Als(next layer) complete
}

// ---------------------------------------------------------------------------
// Fused: layer0 init -> L1 -> L2 -> final dot + loss partials. 32 pts/block,
// 512 threads (8 waves).
// ---------------------------------------------------------------------------
__global__ __launch_bounds__(512) void pois_fused(
    const float* __restrict__ x_int, const float* __restrict__ x_bnd,
    const float* __restrict__ W0, const float* __restrict__ b0,
    const _Float16* __restrict__ W1h, const float* __restrict__ b1,
    const _Float16* __restrict__ W2h, const float* __restrict__ b2,
    const float* __restrict__ W3, const float* __restrict__ b3,
    float* __restrict__ partials, int NI, int NT, int nblk)
{
    __shared__ _Float16 Als[4][PPB][KP];     // [state][p][k], 133 KB
    __shared__ float sc[64];

    const int tid = threadIdx.x;
    const int wv = tid >> 6, lane = tid & 63;
    const int p0 = blockIdx.x * PPB;

    // ---- layer 0: thread (p = tid&31, kc = tid>>5) covers 32 k ----
    {
        const int p = tid & 31, kc = tid >> 5;
        int gp = p0 + p;
        int gpc = (gp >= NT) ? 0 : gp;
        float xx, yy;
        if (gpc < NI) { xx = x_int[2 * gpc];        yy = x_int[2 * gpc + 1]; }
        else          { xx = x_bnd[2 * (gpc - NI)]; yy = x_bnd[2 * (gpc - NI) + 1]; }
        #pragma unroll
        for (int k8 = 0; k8 < 4; ++k8) {
            const int k = kc * 32 + k8 * 8;
            f32x4 w0a = *(const f32x4*)&W0[k],       w0b = *(const f32x4*)&W0[k + 4];
            f32x4 w1a = *(const f32x4*)&W0[HID + k], w1b = *(const f32x4*)&W0[HID + k + 4];
            f32x4 b0a = *(const f32x4*)&b0[k],       b0b = *(const f32x4*)&b0[k + 4];
            half8 vh, vt1, vt2, vS;
            #pragma unroll
            for (int i = 0; i < 8; ++i) {
                float w0i = (i < 4) ? w0a[i] : w0b[i - 4];
                float w1i = (i < 4) ? w1a[i] : w1b[i - 4];
                float bbi = (i < 4) ? b0a[i] : b0b[i - 4];
                float a = fast_tanh(xx * w0i + yy * w1i + bbi);
                float g = 1.f - a * a;
                vh[i]  = (_Float16)a;
                vt1[i] = (_Float16)(g * w0i);
                vt2[i] = (_Float16)(g * w1i);
                vS[i]  = (_Float16)(-2.f * a * g * (w0i * w0i + w1i * w1i));
            }
            *(half8*)&Als[0][p][k] = vh;
            *(half8*)&Als[1][p][k] = vt1;
            *(half8*)&Als[2][p][k] = vt2;
            *(half8*)&Als[3][p][k] = vS;
        }
    }
    __syncthreads();

    layer_pass<true >(W1h, b1, Als, wv, lane);
    layer_pass<false>(W2h, b2, Als, wv, lane);

    // ---- final: u = h.W3 + b3 ; lap = S.W3 ; loss partials ----
    {
        const int psub = lane >> 4, kc = lane & 15;
        const int p = wv * 4 + psub;
        float u = 0.f, lap = 0.f;
        #pragma unroll
        for (int k8 = 0; k8 < 4; ++k8) {
            const int k = kc * 32 + k8 * 8;
            half8 hh = *(const half8*)&Als[0][p][k];
            half8 ss = *(const half8*)&Als[3][p][k];
            f32x4 wa = *(const f32x4*)&W3[k], wb = *(const f32x4*)&W3[k + 4];
            #pragma unroll
            for (int i = 0; i < 8; ++i) {
                float w = (i < 4) ? wa[i] : wb[i - 4];
                u   += (float)hh[i] * w;
                lap += (float)ss[i] * w;
            }
        }
        #pragma unroll
        for (int off = 1; off < 16; off <<= 1) {
            u   += __shfl_xor(u, off);
            lap += __shfl_xor(lap, off);
        }
        if (kc == 0) {
            int gp = p0 + p;
            float vi = 0.f, vb = 0.f;
            if (gp < NI) {
                const float PIf = 3.14159265358979323846f;
                float xx = x_int[2 * gp], yy = x_int[2 * gp + 1];
                float sx = sinf(PIf * xx);
                float y2 = yy * yy;
                float sy = sinf(PIf * y2), cy = cosf(PIf * y2);
                float f = -PIf * PIf * (1.f + 4.f * y2) * sx * sy + 2.f * PIf * sx * cy;
                float r = lap - f;
                vi = r * r;
            } else if (gp < NT) {
                float uu = u + b3[0];
                vb = uu * uu;
            }
            sc[p * 2] = vi; sc[p * 2 + 1] = vb;
        }
    }
    __syncthreads();
    if (tid == 0) {
        float svi = 0.f, svb = 0.f;
        #pragma unroll
        for (int p = 0; p < PPB; ++p) { svi += sc[p * 2]; svb += sc[p * 2 + 1]; }
        partials[blockIdx.x] = svi;
        partials[nblk + blockIdx.x] = svb;
    }
}

// ---------------------------------------------------------------------------
// Deterministic final reduction (no atomics)
// ---------------------------------------------------------------------------
__global__ __launch_bounds__(256) void pois_reduce(
    const float* __restrict__ partials, float* __restrict__ out,
    int nblk, int NI, int NB)
{
    int tid = threadIdx.x;
    float si = 0.f, sb = 0.f;
    for (int i = tid; i < nblk; i += 256) {
        si += partials[i];
        sb += partials[nblk + i];
    }
    #pragma unroll
    for (int off = 32; off > 0; off >>= 1) {
        si += __shfl_xor(si, off);
        sb += __shfl_xor(sb, off);
    }
    __shared__ float ri[4], rb[4];
    int wv = tid >> 6;
    if ((tid & 63) == 0) { ri[wv] = si; rb[wv] = sb; }
    __syncthreads();
    if (tid == 0) {
        float inter = (ri[0] + ri[1] + ri[2] + ri[3]) / (float)NI;
        float bound = (rb[0] + rb[1] + rb[2] + rb[3]) / (float)NB;
        out[0] = 0.01f * inter + bound;   // ALPHA = 0.01
        out[1] = inter;
        out[2] = bound;
    }
}

// ---------------------------------------------------------------------------
extern "C" void kernel_launch(void* const* d_in, const int* in_sizes, int n_in,
                              void* d_out, int out_size, void* d_ws, size_t ws_size,
                              hipStream_t stream)
{
    const float* x_int = (const float*)d_in[0];
    const float* x_bnd = (const float*)d_in[1];
    const float* W0 = (const float*)d_in[2];
    const float* b0 = (const float*)d_in[3];
    const float* W1 = (const float*)d_in[4];
    const float* b1 = (const float*)d_in[5];
    const float* W2 = (const float*)d_in[6];
    const float* b2 = (const float*)d_in[7];
    const float* W3 = (const float*)d_in[8];
    const float* b3 = (const float*)d_in[9];

    int NI = in_sizes[0] / 2;    // 20000
    int NB = in_sizes[1] / 2;    // 800
    int NT = NI + NB;            // 20800
    int nblk = (NT + PPB - 1) / PPB;   // 650

    // ws: [partials 16KB][W1h 512KB][W2h 512KB]
    float* partials = (float*)d_ws;
    _Float16* W1h = (_Float16*)((char*)d_ws + 16384);
    _Float16* W2h = W1h + 262144;

    prep_wt<<<1024, 256, 0, stream>>>(W1, W1h);
    prep_wt<<<1024, 256, 0, stream>>>(W2, W2h);

    pois_fused<<<nblk, 512, 0, stream>>>(
        x_int, x_bnd, W0, b0, W1h, b1, W2h, b2, W3, b3,
        partials, NI, NT, nblk);

    pois_reduce<<<1, 256, 0, stream>>>(partials, (float*)d_out, nblk, NI, NB);
}